// Round 7
// baseline (16395.590 us; speedup 1.0000x reference)
//
#include <hip/hip_runtime.h>
#include <hip/hip_bf16.h>
#include <stdint.h>

#define HID     1024
#define NSTEP   4096
#define NBLK    256
#define WAVES   4
#define THREADS (WAVES * 64)
#define LDSBYTES 90112   // 64KB weights + 8KB h dbuf + pad -> forces 1 block/CU

typedef unsigned int u32x4 __attribute__((ext_vector_type(4)));
typedef float        f32x4 __attribute__((ext_vector_type(4)));

// ---------------- ws layout ----------------
// [0, 16MiB)               W' = W_hh + W_ih @ W_dec   (4096 x 1024 f32)
// [16MiB, +16KiB)          b' = b_ih+b_hh+W_ih@b_dec  (4096 f32)
// [.. +16KiB)              ginit = W_ih@x + b_ih+b_hh (4096 f32)
// [.. +16KiB)              hbuf: 2 slots x 1024 x u64 {val,tag}
// [16MiB+64KiB, +16MiB)    H history: 4096 x 1024 f32

__device__ __forceinline__ float d4v(f32x4 a, f32x4 b) {
    return fmaf(a.x, b.x, fmaf(a.y, b.y, fmaf(a.z, b.z, a.w * b.w)));
}

// full-wave64 sum via DPP (VALU pipe only; result broadcast via readlane SGPR)
__device__ __forceinline__ float wave_sum64(float x) {
#define DPPADD(ctrl, rmask)                                                     \
    x += __int_as_float(__builtin_amdgcn_update_dpp(                            \
        0, __float_as_int(x), (ctrl), (rmask), 0xf, true));
    DPPADD(0x111, 0xf)   // row_shr:1
    DPPADD(0x112, 0xf)   // row_shr:2
    DPPADD(0x114, 0xf)   // row_shr:4
    DPPADD(0x118, 0xf)   // row_shr:8  -> lane15 of each row16 = row sum
    DPPADD(0x142, 0xa)   // row_bcast15 -> rows 1,3 accumulate prev row
    DPPADD(0x143, 0xc)   // row_bcast31 -> rows 2,3 accumulate rows 0-1
#undef DPPADD
    return __int_as_float(__builtin_amdgcn_readlane(__float_as_int(x), 63));
}

// ---- prep: b', ginit, clear tags ----
__global__ void k_prep(const float* __restrict__ x, const float* __restrict__ Wih,
                       const float* __restrict__ bih, const float* __restrict__ bhh,
                       const float* __restrict__ bdec,
                       float* __restrict__ bp, float* __restrict__ gi,
                       unsigned long long* __restrict__ hbuf) {
    int i = blockIdx.x * 256 + threadIdx.x;   // 0 .. 8191
    if (i < 4096) {
        float base = bih[i] + bhh[i];
        float s_b = base, s_g = base;
#pragma unroll
        for (int d = 0; d < 11; ++d) {
            float w = Wih[i * 11 + d];
            s_b = fmaf(w, bdec[d], s_b);
            s_g = fmaf(w, x[d], s_g);
        }
        bp[i] = s_b;
        gi[i] = s_g;
    }
    if (i < 2 * 1024) hbuf[i] = 0ULL;         // clear both parity slots
}

// ---- fold: W' = W_hh + W_ih @ W_dec ----
__global__ void k_fold(const float* __restrict__ Wih, const float* __restrict__ Whh,
                       const float* __restrict__ Wdec, float* __restrict__ Wp) {
    int idx = blockIdx.x * 256 + threadIdx.x;       // 0 .. 4M-1
    int r = idx >> 10, k = idx & 1023;
    float acc = Whh[idx];
#pragma unroll
    for (int d = 0; d < 11; ++d)
        acc = fmaf(Wih[r * 11 + d], Wdec[d * HID + k], acc);
    Wp[idx] = acc;
}

// ---- the sequential LSTM recurrence: 256 blocks, 1 unit/wave, weights in LDS ----
__global__ __launch_bounds__(THREADS) void lstm_seq(
    const float* __restrict__ Wp, const float* __restrict__ bp,
    const float* __restrict__ gi, unsigned long long* hbuf,
    float* __restrict__ Hh) {
    extern __shared__ float smem[];
    float* wLds = smem;            // [4 units][4 gates][1024] f32 = 16384 f32 = 64KB
    float* hsL  = smem + 16384;    // [2][1024] h double-buffer (8KB)

    const int tid  = threadIdx.x;
    const int wv   = tid >> 6;
    const int lane = tid & 63;
    const int unit = blockIdx.x * WAVES + wv;

    // ---- one-time: stage this block's 4 units x 4 gates of W' into LDS ----
    // float4 index v in [0,4096): ug = v>>8 in [0,16) -> (uu = ug>>2, q = ug&3),
    // k4 = v&255. LDS float4 layout: v = uu*1024 + q*256 + k4.
    {
        const float4* Wp4 = (const float4*)Wp;
        float4* wl4 = (float4*)wLds;
        for (int v = tid; v < 4096; v += THREADS) {
            int ug = v >> 8;
            int uu = ug >> 2, q = ug & 3;
            int k4 = v & 255;
            size_t row = (size_t)(blockIdx.x * WAVES + uu) + ((size_t)q << 10);
            wl4[v] = Wp4[row * 256 + k4];
        }
    }
    __syncthreads();

    float bpv[4], giv[4];
#pragma unroll
    for (int q = 0; q < 4; ++q) {
        bpv[q] = bp[unit + q * 1024];
        giv[q] = gi[unit + q * 1024];
    }

    // per-wave LDS weight base: gate q, chunk j at f32x4 index wv*1024 + q*256 + lane + 64*j
    const f32x4* wl = (const f32x4*)wLds + (size_t)wv * 1024;

    float c = 0.f;

#pragma unroll 1
    for (int t = 1; t <= NSTEP; ++t) {
        float s[4];
        if (t == 1) {
            // h_0 = 0: gates are exactly ginit, no sync needed
#pragma unroll
            for (int q = 0; q < 4; ++q) s[q] = giv[q];
        } else {
            const int slot = (t - 1) & 1;
            // poll: thread owns 4 pairs (32B) = h[4*tid .. 4*tid+3]
            const unsigned long long* src = hbuf + slot * HID + 4 * tid;
            const unsigned want = (unsigned)(t - 1);
            u32x4 a, b;
            do {
                asm volatile("global_load_dwordx4 %0, %2, off sc1\n\t"
                             "global_load_dwordx4 %1, %3, off sc1\n\t"
                             "s_waitcnt vmcnt(0)"
                             : "=&v"(a), "=&v"(b)
                             : "v"(src), "v"(src + 2) : "memory");
            } while (a.y != want || a.w != want || b.y != want || b.w != want);
            *(float4*)&hsL[slot * HID + 4 * tid] =
                make_float4(__uint_as_float(a.x), __uint_as_float(a.z),
                            __uint_as_float(b.x), __uint_as_float(b.z));
            __syncthreads();

            const f32x4* h4 = (const f32x4*)&hsL[slot * HID];
            f32x4 h0 = h4[lane], h1 = h4[lane + 64], h2 = h4[lane + 128], h3 = h4[lane + 192];
#pragma unroll
            for (int q = 0; q < 4; ++q) {
                const f32x4* wq = wl + q * 256;
                float d = d4v(wq[lane], h0) + d4v(wq[lane + 64], h1)
                        + d4v(wq[lane + 128], h2) + d4v(wq[lane + 192], h3);
                s[q] = wave_sum64(d) + bpv[q];
            }
        }

        // pointwise LSTM (uniform across lanes; c register-resident)
        float I = 1.f / (1.f + __expf(-s[0]));
        float F = 1.f / (1.f + __expf(-s[1]));
        float G = 1.f - 2.f / (__expf(2.f * s[2]) + 1.f);   // tanh
        float O = 1.f / (1.f + __expf(-s[3]));
        c = fmaf(F, c, I * G);
        float h = O * (1.f - 2.f / (__expf(2.f * c) + 1.f));

        if (lane == 0) {
            Hh[(size_t)(t - 1) * HID + unit] = h;   // history for decoder
            unsigned long long pair =
                ((unsigned long long)(unsigned)t << 32) | (unsigned long long)__float_as_uint(h);
            __hip_atomic_store(hbuf + (t & 1) * HID + unit, pair,
                               __ATOMIC_RELAXED, __HIP_MEMORY_SCOPE_AGENT);
        }
    }
}

// ---- decoder over the whole history: out[r][d] = W_dec[d] . H[r] + b_dec[d] ----
__global__ void k_dec(const float* __restrict__ Hh, const float* __restrict__ Wdec,
                      const float* __restrict__ bdec, float* __restrict__ out) {
    int idx = blockIdx.x * 256 + threadIdx.x;
    if (idx >= NSTEP * 11) return;
    int r = idx / 11, d = idx - r * 11;
    const float4* h4 = (const float4*)(Hh + (size_t)r * HID);
    const float4* w4 = (const float4*)(Wdec + (size_t)d * HID);
    float acc = 0.f;
#pragma unroll 4
    for (int k = 0; k < HID / 4; ++k) {
        float4 a = h4[k], b = w4[k];
        acc = fmaf(a.x, b.x, fmaf(a.y, b.y, fmaf(a.z, b.z, fmaf(a.w, b.w, acc))));
    }
    out[idx] = acc + bdec[d];
}

extern "C" void kernel_launch(void* const* d_in, const int* in_sizes, int n_in,
                              void* d_out, int out_size, void* d_ws, size_t ws_size,
                              hipStream_t stream) {
    const float* x    = (const float*)d_in[0];
    const float* Wih  = (const float*)d_in[1];
    const float* Whh  = (const float*)d_in[2];
    const float* bih  = (const float*)d_in[3];
    const float* bhh  = (const float*)d_in[4];
    const float* Wdec = (const float*)d_in[5];
    const float* bdec = (const float*)d_in[6];
    float* out = (float*)d_out;

    char* ws = (char*)d_ws;
    float* Wp = (float*)ws;                                      // 16 MiB
    float* bp = (float*)(ws + (16u << 20));                      // 16 KiB
    float* gi = bp + 4096;                                       // 16 KiB
    unsigned long long* hbuf = (unsigned long long*)(gi + 4096); // 16 KiB
    float* Hh = (float*)(ws + (16u << 20) + (64u << 10));        // 16 MiB

    // allow >64KB dynamic LDS (idempotent; harmless if already set)
    (void)hipFuncSetAttribute((const void*)lstm_seq,
                              hipFuncAttributeMaxDynamicSharedMemorySize, LDSBYTES);

    k_prep<<<32, 256, 0, stream>>>(x, Wih, bih, bhh, bdec, bp, gi, hbuf);
    k_fold<<<(4096 * 1024) / 256, 256, 0, stream>>>(Wih, Whh, Wdec, Wp);
    lstm_seq<<<NBLK, THREADS, LDSBYTES, stream>>>(Wp, bp, gi, hbuf, Hh);
    k_dec<<<(NSTEP * 11 + 255) / 256, 256, 0, stream>>>(Hh, Wdec, bdec, out);
}